// Round 2
// baseline (495.045 us; speedup 1.0000x reference)
//
#include <hip/hip_runtime.h>

#define S_    2048
#define N_    16
#define OBS_  8
#define PRED_ 12
#define B_    (S_*N_)

typedef __attribute__((ext_vector_type(8))) short short8;
typedef __attribute__((ext_vector_type(4))) float floatx4;
typedef unsigned short ushort_t;

__device__ __forceinline__ float4 ld4(const float* p) { return *(const float4*)p; }
__device__ __forceinline__ float sigmf(float x) { return __builtin_amdgcn_rcpf(1.0f + __expf(-x)); }
__device__ __forceinline__ float tanhx(float x) { return fmaf(-2.0f, __builtin_amdgcn_rcpf(1.0f + __expf(2.0f*x)), 1.0f); }
// f32 -> bf16 round-to-nearest-even (unbiased: autoregressive loop compounds bias)
__device__ __forceinline__ ushort_t f2bf(float f) {
  union { float f; unsigned u; } v; v.f = f;
  unsigned r = v.u + 0x7FFFu + ((v.u >> 16) & 1u);
  return (ushort_t)(r >> 16);
}

__device__ __forceinline__ float dot16w(const float* w, const float4 x0, const float4 x1,
                                        const float4 x2, const float4 x3) {
  float4 w0 = ld4(w); float4 w1 = ld4(w+4); float4 w2 = ld4(w+8); float4 w3 = ld4(w+12);
  float a = x0.x*w0.x + x0.y*w0.y + x0.z*w0.z + x0.w*w0.w;
  float b = x1.x*w1.x + x1.y*w1.y + x1.z*w1.z + x1.w*w1.w;
  float c = x2.x*w2.x + x2.y*w2.y + x2.z*w2.z + x2.w*w2.w;
  float d = x3.x*w3.x + x3.y*w3.y + x3.z*w3.z + x3.w*w3.w;
  return (a+b)+(c+d);
}

// one scene per block; thread (i = agent, k = hidden unit), 256 threads.
// h/e/ctx/prev rows are wave-private (wave w owns agents 4w..4w+3) -> same-wave
// in-order DS pipe makes them barrier-free; only hb (pool h) and pos cross waves.
extern "C" __global__ __launch_bounds__(256, 4) void traj_ar_kernel(
    const float* __restrict__ traj_rel, const float* __restrict__ obs_pos,
    const int*  __restrict__ nei,       const float* __restrict__ noise,
    const float* __restrict__ eeW, const float* __restrict__ eeb,
    const float* __restrict__ eWi, const float* __restrict__ eWh, const float* __restrict__ eb,
    const float* __restrict__ diW, const float* __restrict__ dib,
    const float* __restrict__ dWi, const float* __restrict__ dWh, const float* __restrict__ db,
    const float* __restrict__ prW, const float* __restrict__ prb,
    const float* __restrict__ mW,  const float* __restrict__ mb,
    const float* __restrict__ oW,  const float* __restrict__ ob,
    float* __restrict__ out)
{
  // LSTM weights transposed, row stride 20 floats (80B: b128-aligned, 2-way alias = free)
  __shared__ __align__(16) float sW_ee[32];
  __shared__ __align__(16) float sb_ee[16];
  __shared__ __align__(16) float sW_eiT[64*20];
  __shared__ __align__(16) float sW_ehT[64*20];
  __shared__ __align__(16) float sb_e[64];
  __shared__ __align__(16) float sW_diT[16*20];
  __shared__ __align__(16) float sb_di[16];
  __shared__ __align__(16) float sW_dWiT[64*20];
  __shared__ __align__(16) float sW_dWhT[64*20];
  __shared__ __align__(16) float sb_d[64];
  __shared__ __align__(16) float sW_pr[32];
  __shared__ __align__(16) float sb_pr[16];
  __shared__ __align__(16) float sW_o[64];
  __shared__ __align__(16) float sb_o[4];
  // state
  __shared__ __align__(16) float h_s[2][256];
  __shared__ __align__(16) float e_s[256];
  __shared__ __align__(16) float ctx_s[256];
  // pool inputs in bf16 for MFMA. re_s: [i][j][m] j-stride 24 ushorts (48B: b128-aligned,
  // j/j+8 2-way bank alias = free), i-stride 392 ushorts (784B, 16B-aligned).
  __shared__ __align__(16) ushort_t re_s[16*392];
  __shared__ __align__(16) ushort_t hb_s[16*24];
  __shared__ __align__(16) float pos_s[32];
  __shared__ __align__(16) float prev_s[32];
  __shared__            unsigned sm_s[16];   // neighbor mask bits per agent

  const int tid = threadIdx.x;
  const int s = blockIdx.x;
  const int i = tid >> 4;
  const int k = tid & 15;
  const int bi = s*N_ + i;

  // ---- stage weights into LDS ----
  if (tid < 32) sW_ee[tid] = eeW[tid];
  if (tid < 16) sb_ee[tid] = eeb[tid];
  for (int idx = tid; idx < 1024; idx += 256) {
    int m = idx >> 6, c = idx & 63;
    sW_eiT[c*20+m] = eWi[idx];
    sW_ehT[c*20+m] = eWh[idx];
    sW_dWiT[c*20+m] = dWi[idx];
    sW_dWhT[c*20+m] = dWh[idx];
  }
  if (tid < 64) sb_e[tid] = eb[tid];
  for (int idx = tid; idx < 288; idx += 256) { int m = idx >> 4, c = idx & 15; sW_diT[c*20+m] = diW[idx]; }
  if (tid < 16) sb_di[tid] = dib[tid];
  if (tid < 64) sb_d[tid] = db[tid];
  if (tid < 32) sW_pr[tid] = prW[tid];
  if (tid < 16) sb_pr[tid] = prb[tid];
  if (tid < 64) sW_o[tid] = oW[tid];
  if (tid < 4)  sb_o[tid] = ob[tid];

  h_s[0][tid] = 0.0f;
  ctx_s[tid] = 0.0f;
  if (k < 2) {
    prev_s[i*2+k] = traj_rel[((OBS_-1)*B_ + bi)*2 + k];
    pos_s[i*2+k]  = obs_pos[((OBS_-1)*B_ + bi)*2 + k];
  }

  // pool-MLP B-fragment (32x16 bf16) + bias in registers; mask bits -> sm_s
  const int lq = (tid & 63) >> 4;       // quad within wave
  const int lc = tid & 15;              // col within wave (== k)
  short8 bfrag;
  #pragma unroll
  for (int jj = 0; jj < 8; ++jj) bfrag[jj] = (short)f2bf(mW[(8*lq + jj)*16 + lc]);
  floatx4 cinit;
  { float bm = mb[lc]; cinit[0]=bm; cinit[1]=bm; cinit[2]=bm; cinit[3]=bm; }

  unsigned long long bal = __ballot(nei[bi*N_ + k] > 0);
  if (k == 0) sm_s[i] = (unsigned)((bal >> (16*(i & 3))) & 0xFFFFull);

  __syncthreads();

  // ---- encoder: 8 LSTM steps (h rows wave-private -> no barriers) ----
  int cur = 0;
  float c_reg = 0.0f;
  const float2* xr2 = (const float2*)traj_rel;
  for (int t = 0; t < OBS_; ++t) {
    float2 x = xr2[t*B_ + bi];
    float em[16];
    #pragma unroll
    for (int m = 0; m < 16; ++m)
      em[m] = fmaxf(fmaf(x.y, sW_ee[16+m], fmaf(x.x, sW_ee[m], sb_ee[m])), 0.0f);
    float4 e0 = make_float4(em[0],em[1],em[2],em[3]);
    float4 e1 = make_float4(em[4],em[5],em[6],em[7]);
    float4 e2 = make_float4(em[8],em[9],em[10],em[11]);
    float4 e3 = make_float4(em[12],em[13],em[14],em[15]);
    const float* hp = &h_s[cur][i*16];
    float4 h0 = ld4(hp), h1 = ld4(hp+4), h2 = ld4(hp+8), h3 = ld4(hp+12);
    float g0 = sb_e[k]    + dot16w(&sW_eiT[(k)*20],    e0,e1,e2,e3) + dot16w(&sW_ehT[(k)*20],    h0,h1,h2,h3);
    float g1 = sb_e[k+16] + dot16w(&sW_eiT[(k+16)*20], e0,e1,e2,e3) + dot16w(&sW_ehT[(k+16)*20], h0,h1,h2,h3);
    float g2 = sb_e[k+32] + dot16w(&sW_eiT[(k+32)*20], e0,e1,e2,e3) + dot16w(&sW_ehT[(k+32)*20], h0,h1,h2,h3);
    float g3 = sb_e[k+48] + dot16w(&sW_eiT[(k+48)*20], e0,e1,e2,e3) + dot16w(&sW_ehT[(k+48)*20], h0,h1,h2,h3);
    float ig = sigmf(g0), fg = sigmf(g1), gv = tanhx(g2), og = sigmf(g3);
    c_reg = fg*c_reg + ig*gv;
    float nh = og * tanhx(c_reg);
    h_s[cur^1][i*16+k] = nh;
    cur ^= 1;
  }

  // ---- decoder: 12 autoregressive steps, 2 barriers/step ----
  c_reg = 0.0f;
  const int MU_OFF = PRED_*B_*2;
  const int SD_OFF = 2*PRED_*B_*2;
  const int w = tid >> 6;
  for (int t = 0; t < PRED_; ++t) {
    // phase 1: e = relu([ctx, prev] @ dec_in_W + b)   (ctx/prev wave-private)
    {
      const float* cx = &ctx_s[i*16];
      float4 c0 = ld4(cx), c1 = ld4(cx+4), c2 = ld4(cx+8), c3 = ld4(cx+12);
      float p0 = prev_s[i*2+0], p1 = prev_s[i*2+1];
      const float* wd = &sW_diT[k*20];
      float acc = sb_di[k] + dot16w(wd, c0,c1,c2,c3) + p0*wd[16] + p1*wd[17];
      e_s[i*16+k] = fmaxf(acc, 0.0f);
    }
    // phase 2: LSTM cell (e/h wave-private); also write bf16 h copy for pool
    {
      const float* ep = &e_s[i*16];
      float4 e0 = ld4(ep), e1 = ld4(ep+4), e2 = ld4(ep+8), e3 = ld4(ep+12);
      const float* hp = &h_s[cur][i*16];
      float4 h0 = ld4(hp), h1 = ld4(hp+4), h2 = ld4(hp+8), h3 = ld4(hp+12);
      float g0 = sb_d[k]    + dot16w(&sW_dWiT[(k)*20],    e0,e1,e2,e3) + dot16w(&sW_dWhT[(k)*20],    h0,h1,h2,h3);
      float g1 = sb_d[k+16] + dot16w(&sW_dWiT[(k+16)*20], e0,e1,e2,e3) + dot16w(&sW_dWhT[(k+16)*20], h0,h1,h2,h3);
      float g2 = sb_d[k+32] + dot16w(&sW_dWiT[(k+32)*20], e0,e1,e2,e3) + dot16w(&sW_dWhT[(k+32)*20], h0,h1,h2,h3);
      float g3 = sb_d[k+48] + dot16w(&sW_dWiT[(k+48)*20], e0,e1,e2,e3) + dot16w(&sW_dWhT[(k+48)*20], h0,h1,h2,h3);
      float ig = sigmf(g0), fg = sigmf(g1), gv = tanhx(g2), og = sigmf(g3);
      c_reg = fg*c_reg + ig*gv;
      float nh = og * tanhx(c_reg);
      h_s[cur^1][i*16+k] = nh;
      hb_s[i*24 + k] = f2bf(nh);
    }
    cur ^= 1;
    // phase 3: re[i][j=k][:] = relu(rel @ prW + b) in bf16  (pos from prev step, barrier E covers)
    {
      float rx = pos_s[i*2+0] - pos_s[k*2+0];
      float ry = pos_s[i*2+1] - pos_s[k*2+1];
      short8 v0, v1;
      #pragma unroll
      for (int m = 0; m < 8; ++m) {
        float a0 = fmaxf(fmaf(ry, sW_pr[16+m], fmaf(rx, sW_pr[m],   sb_pr[m])),   0.0f);
        float a1 = fmaxf(fmaf(ry, sW_pr[24+m], fmaf(rx, sW_pr[8+m], sb_pr[8+m])), 0.0f);
        v0[m] = (short)f2bf(a0);
        v1[m] = (short)f2bf(a1);
      }
      ushort_t* rp = &re_s[i*392 + k*24];
      *(short8*)rp = v0;
      *((short8*)rp + 1) = v1;
    }
    __syncthreads(); // B: hb_s written by all waves before pool reads it
    // phase 4: masked max-pool via MFMA. Tile = agent it; A[j][0:16]=re[it][j], A[j][16:32]=h[j].
    {
      const ushort_t* hbp = &hb_s[lc*24 + (lq-2)*8];
      float ctxv0=0.f, ctxv1=0.f, ctxv2=0.f, ctxv3=0.f;
      #pragma unroll
      for (int tt = 0; tt < 4; ++tt) {
        const int it = 4*w + tt;
        const ushort_t* rep = &re_s[it*392 + lc*24 + lq*8];
        const ushort_t* ap = (lq < 2) ? rep : hbp;
        short8 a = *(const short8*)ap;
        floatx4 d = __builtin_amdgcn_mfma_f32_16x16x32_bf16(a, bfrag, cinit, 0, 0, 0);
        const unsigned mi = sm_s[it];
        float pm = -1e30f;
        #pragma unroll
        for (int r = 0; r < 4; ++r) {
          float feat = fmaxf(d[r], 0.0f);            // row j = lq*4+r, col k = lc
          bool on = (mi >> (lq*4 + r)) & 1u;
          pm = on ? fmaxf(pm, feat) : pm;
        }
        pm = fmaxf(pm, __shfl_xor(pm, 16, 64));
        pm = fmaxf(pm, __shfl_xor(pm, 32, 64));
        float cv = (mi != 0u) ? pm : 0.0f;
        if (tt==0) ctxv0=cv; else if (tt==1) ctxv1=cv; else if (tt==2) ctxv2=cv; else ctxv3=cv;
      }
      float cw = (lq==0)?ctxv0:(lq==1)?ctxv1:(lq==2)?ctxv2:ctxv3;
      ctx_s[(4*w + lq)*16 + lc] = cw;   // wave-private rows; consumed by phases 5/1 same wave
    }
    // phase 5: o4 = (h+ctx)@out_W + b; outputs; advance pos/prev
    {
      float o4v = 0.0f;
      if (k < 4) {
        const float* hp = &h_s[cur][i*16];
        const float* cx = &ctx_s[i*16];
        float acc = sb_o[k];
        #pragma unroll
        for (int m = 0; m < 16; ++m) acc = fmaf(hp[m]+cx[m], sW_o[m*4+k], acc);
        o4v = acc;
      }
      float sc = __shfl_down(o4v, 2, 64);
      if (k < 2) {
        float mu = o4v;
        float scale = fminf(fmaxf(sc, -9.0f), 4.0f);
        float sd = __expf(scale);
        float nz = noise[(t*B_ + bi)*2 + k];
        float pr = fmaf(sd, nz, mu);
        int o = (t*B_ + bi)*2 + k;
        out[o]          = pr;
        out[MU_OFF + o] = mu;
        out[SD_OFF + o] = sd;
        pos_s[i*2+k] += pr;
        prev_s[i*2+k] = pr;
      }
    }
    __syncthreads(); // E: pos_s cross-wave for next step's phase 3
  }
}

extern "C" void kernel_launch(void* const* d_in, const int* in_sizes, int n_in,
                              void* d_out, int out_size, void* d_ws, size_t ws_size,
                              hipStream_t stream) {
  (void)in_sizes; (void)n_in; (void)d_ws; (void)ws_size; (void)out_size;
  traj_ar_kernel<<<dim3(S_), dim3(256), 0, stream>>>(
      (const float*)d_in[0],  (const float*)d_in[1],  (const int*)d_in[2],   (const float*)d_in[3],
      (const float*)d_in[4],  (const float*)d_in[5],  (const float*)d_in[6], (const float*)d_in[7],
      (const float*)d_in[8],  (const float*)d_in[9],  (const float*)d_in[10],(const float*)d_in[11],
      (const float*)d_in[12], (const float*)d_in[13], (const float*)d_in[14],(const float*)d_in[15],
      (const float*)d_in[16], (const float*)d_in[17], (const float*)d_in[18],(const float*)d_in[19],
      (float*)d_out);
}